// Round 1
// baseline (577.638 us; speedup 1.0000x reference)
//
#include <hip/hip_runtime.h>
#include <cstddef>

// ---------------- problem constants (match reference) ----------------
#define NB   4
#define NN_  6
#define ND_  41
#define NFH  16
#define NFW  44
#define NC   64
#define NX0_ 200
#define NX1_ 200
#define NVOX   (NB * NX0_ * NX1_)          // 160000 voxels (z is 1)
#define NPRIME (NB * NN_ * ND_ * NFH * NFW) // 692736 points

// ---------------- workspace layout (float/int32 slots) ----------------
#define MATS_OFF   0                        // 24*(b,n): M[9], Pinv[9], trans[3], post_trans[3]
#define COUNT_OFF  1024
#define FILL_OFF   (COUNT_OFF + NVOX)
#define OFFSET_OFF (FILL_OFF + NVOX)
#define BSUM_OFF   (OFFSET_OFF + NVOX)
#define BOFF_OFF   (BSUM_OFF + 1024)
#define PIDX_OFF   (BOFF_OFF + 1024)
#define PLIST_OFF  (PIDX_OFF + NPRIME)
#define WS_FLOATS  (PLIST_OFF + NPRIME)     // ~1.87M * 4B = ~7.5 MB

// 3x3 inverse via adjugate. For the inputs in this problem (pinhole K with
// integer entries, identity post_rots) every cofactor/determinant is exact in
// f32 and each division is correctly rounded -> bit-identical to LAPACK sgetri.
__device__ __forceinline__ void inv3(const float* a, float* inv) {
    float c00 = __fsub_rn(__fmul_rn(a[4], a[8]), __fmul_rn(a[5], a[7]));
    float c01 = __fsub_rn(__fmul_rn(a[5], a[6]), __fmul_rn(a[3], a[8]));
    float c02 = __fsub_rn(__fmul_rn(a[3], a[7]), __fmul_rn(a[4], a[6]));
    float det = __fadd_rn(__fadd_rn(__fmul_rn(a[0], c00), __fmul_rn(a[1], c01)),
                          __fmul_rn(a[2], c02));
    inv[0] = __fdiv_rn(c00, det);
    inv[1] = __fdiv_rn(__fsub_rn(__fmul_rn(a[2], a[7]), __fmul_rn(a[1], a[8])), det);
    inv[2] = __fdiv_rn(__fsub_rn(__fmul_rn(a[1], a[5]), __fmul_rn(a[2], a[4])), det);
    inv[3] = __fdiv_rn(c01, det);
    inv[4] = __fdiv_rn(__fsub_rn(__fmul_rn(a[0], a[8]), __fmul_rn(a[2], a[6])), det);
    inv[5] = __fdiv_rn(__fsub_rn(__fmul_rn(a[2], a[3]), __fmul_rn(a[0], a[5])), det);
    inv[6] = c02 == 0.0f ? __fdiv_rn(c02, det) : __fdiv_rn(c02, det);
    inv[7] = __fdiv_rn(__fsub_rn(__fmul_rn(a[1], a[6]), __fmul_rn(a[0], a[7])), det);
    inv[8] = __fdiv_rn(__fsub_rn(__fmul_rn(a[0], a[4]), __fmul_rn(a[1], a[3])), det);
}

// Per-(b,n) matrix setup: M = rots @ inv(intrins), Pinv = inv(post_rots).
// Sequential non-fma 3-term dots to mirror numpy's batched-matmul gufunc.
__global__ void setup_kernel(const float* __restrict__ rots,
                             const float* __restrict__ trans,
                             const float* __restrict__ intrins,
                             const float* __restrict__ post_rots,
                             const float* __restrict__ post_trans,
                             float* __restrict__ mats) {
    int t = threadIdx.x;
    if (t >= NB * NN_) return;
    const float* R  = rots      + t * 9;
    const float* K  = intrins   + t * 9;
    const float* PR = post_rots + t * 9;
    float Kinv[9], Pinv[9];
    inv3(K, Kinv);
    inv3(PR, Pinv);
    float* o = mats + t * 24;
    for (int i = 0; i < 3; ++i)
        for (int k = 0; k < 3; ++k) {
            float s = __fmul_rn(R[i * 3 + 0], Kinv[0 * 3 + k]);
            s = __fadd_rn(s, __fmul_rn(R[i * 3 + 1], Kinv[1 * 3 + k]));
            s = __fadd_rn(s, __fmul_rn(R[i * 3 + 2], Kinv[2 * 3 + k]));
            o[i * 3 + k] = s;
        }
    for (int i = 0; i < 9; ++i) o[9 + i] = Pinv[i];
    o[18] = trans[t * 3 + 0];
    o[19] = trans[t * 3 + 1];
    o[20] = trans[t * 3 + 2];
    o[21] = post_trans[t * 3 + 0];
    o[22] = post_trans[t * 3 + 1];
    o[23] = post_trans[t * 3 + 2];
}

// Compute voxel flat index for point p, or -1 if dropped.
// Op order mirrors the reference exactly; all muls/adds via _rn intrinsics so
// the compiler cannot contract to fma (ref has no fma in np path).
__device__ __forceinline__ int compute_idx(int p, const float* __restrict__ mats) {
    int w = p % NFW; int t = p / NFW;
    int h = t % NFH; t /= NFH;
    int d = t % ND_; t /= ND_;
    int n = t % NN_; int b = t / NN_;
    const float* mp = mats + (b * NN_ + n) * 24;

    // np.linspace computes in f64 then casts to f32 (endpoint forced to stop)
    float u   = (w == NFW - 1) ? 703.0f : (float)((double)w * (703.0 / 43.0));
    float v   = __fmul_rn((float)h, 17.0f);   // 255/15 == 17 exactly
    float dep = (float)(4 + d);               // arange(4,45,1): exact ints

    float f0 = __fsub_rn(u, mp[21]);
    float f1 = __fsub_rn(v, mp[22]);
    float f2 = __fsub_rn(dep, mp[23]);

    float q0 = __fadd_rn(__fadd_rn(__fmul_rn(mp[9],  f0), __fmul_rn(mp[10], f1)), __fmul_rn(mp[11], f2));
    float q1 = __fadd_rn(__fadd_rn(__fmul_rn(mp[12], f0), __fmul_rn(mp[13], f1)), __fmul_rn(mp[14], f2));
    float q2 = __fadd_rn(__fadd_rn(__fmul_rn(mp[15], f0), __fmul_rn(mp[16], f1)), __fmul_rn(mp[17], f2));

    float r0 = __fmul_rn(q0, q2);
    float r1 = __fmul_rn(q1, q2);

    float g0 = __fadd_rn(__fadd_rn(__fadd_rn(__fmul_rn(mp[0], r0), __fmul_rn(mp[1], r1)), __fmul_rn(mp[2], q2)), mp[18]);
    float g1 = __fadd_rn(__fadd_rn(__fadd_rn(__fmul_rn(mp[3], r0), __fmul_rn(mp[4], r1)), __fmul_rn(mp[5], q2)), mp[19]);
    float g2 = __fadd_rn(__fadd_rn(__fadd_rn(__fmul_rn(mp[6], r0), __fmul_rn(mp[7], r1)), __fmul_rn(mp[8], q2)), mp[20]);

    // (geom - (BX - DX/2)) / DX ; BX-DX/2 = (-50,-50,-10) exactly in f32
    float s0 = __fdiv_rn(__fsub_rn(g0, -50.0f), 0.5f);
    float s1 = __fdiv_rn(__fsub_rn(g1, -50.0f), 0.5f);
    float s2 = __fdiv_rn(__fsub_rn(g2, -10.0f), 20.0f);
    s0 = fminf(fmaxf(s0, -1e6f), 1e6f);
    s1 = fminf(fmaxf(s1, -1e6f), 1e6f);
    s2 = fminf(fmaxf(s2, -1e6f), 1e6f);
    int i0 = (int)s0;   // trunc toward zero, matches jnp.trunc().astype(int32)
    int i1 = (int)s1;
    int i2 = (int)s2;
    if (i0 >= 0 && i0 < NX0_ && i1 >= 0 && i1 < NX1_ && i2 >= 0 && i2 < 1)
        return b * (NX0_ * NX1_) + i2 * (NX0_ * NX1_) + i0 * NX1_ + i1;
    return -1;
}

// Phase 1: per-point voxel id + histogram
__global__ __launch_bounds__(256) void geom_kernel(const float* __restrict__ mats,
                                                   int* __restrict__ pidx,
                                                   int* __restrict__ count) {
    int p = blockIdx.x * 256 + threadIdx.x;   // NPRIME divisible by 256
    int idx = compute_idx(p, mats);
    pidx[p] = idx;
    if (idx >= 0) atomicAdd(&count[idx], 1);
}

// Phase 2: exclusive scan of 160000 counts (3 small kernels)
__global__ __launch_bounds__(256) void scan1(const int* __restrict__ count,
                                             int* __restrict__ offset,
                                             int* __restrict__ bsum) {
    __shared__ int s[256];
    int tid = threadIdx.x;
    int base = blockIdx.x * 256;
    int v = count[base + tid];
    int acc = v;
    s[tid] = acc;
    __syncthreads();
    for (int o = 1; o < 256; o <<= 1) {
        int add = (tid >= o) ? s[tid - o] : 0;
        __syncthreads();
        acc += add;
        s[tid] = acc;
        __syncthreads();
    }
    offset[base + tid] = acc - v;
    if (tid == 255) bsum[blockIdx.x] = acc;
}

__global__ __launch_bounds__(1024) void scan2(const int* __restrict__ bsum,
                                              int* __restrict__ boff, int nblk) {
    __shared__ int s[1024];
    int tid = threadIdx.x;
    int v = (tid < nblk) ? bsum[tid] : 0;
    int acc = v;
    s[tid] = acc;
    __syncthreads();
    for (int o = 1; o < 1024; o <<= 1) {
        int add = (tid >= o) ? s[tid - o] : 0;
        __syncthreads();
        acc += add;
        s[tid] = acc;
        __syncthreads();
    }
    if (tid < nblk) boff[tid] = acc - v;
}

__global__ __launch_bounds__(256) void scan3(int* __restrict__ offset,
                                             const int* __restrict__ boff) {
    int i = blockIdx.x * 256 + threadIdx.x;
    offset[i] += boff[blockIdx.x];
}

// Phase 3: bucket points per voxel
__global__ __launch_bounds__(256) void fill_kernel(const int* __restrict__ pidx,
                                                   const int* __restrict__ offset,
                                                   int* __restrict__ fill,
                                                   int* __restrict__ plist) {
    int p = blockIdx.x * 256 + threadIdx.x;
    int idx = pidx[p];
    if (idx < 0) return;
    int pos = atomicAdd(&fill[idx], 1);
    plist[offset[idx] + pos] = p;
}

// Phase 4: gather-pool. One wave per voxel, lane = channel.
// Reads of x are 256B fully-coalesced per wave; each output element written
// exactly once (zero for empty voxels) -> no float atomics, no out memset.
__global__ __launch_bounds__(256) void pool_kernel(const float* __restrict__ x,
                                                   const int* __restrict__ plist,
                                                   const int* __restrict__ offset,
                                                   const int* __restrict__ count,
                                                   float* __restrict__ out) {
    int v = blockIdx.x * 4 + (threadIdx.x >> 6);  // NVOX divisible by 4
    int lane = threadIdx.x & 63;
    int start = offset[v];
    int cnt = count[v];
    float sum = 0.0f;
    for (int i = 0; i < cnt; ++i) {
        int p = plist[start + i];
        sum += x[(size_t)p * NC + lane];
    }
    int b = v / (NX0_ * NX1_);
    int xy = v % (NX0_ * NX1_);
    out[((size_t)(b * NC + lane)) * (NX0_ * NX1_) + xy] = sum;
}

// Fallback (only if ws too small): direct float atomics into out.
__global__ __launch_bounds__(256) void scatter_direct(const float* __restrict__ x,
                                                      const float* __restrict__ mats,
                                                      float* __restrict__ out) {
    int wave = blockIdx.x * 4 + (threadIdx.x >> 6);
    int lane = threadIdx.x & 63;
    int idx = compute_idx(wave, mats);
    if (idx < 0) return;
    int b = idx / (NX0_ * NX1_);
    int xy = idx % (NX0_ * NX1_);
    float f = x[(size_t)wave * NC + lane];
    atomicAdd(out + ((size_t)(b * NC + lane)) * (NX0_ * NX1_) + xy, f);
}

extern "C" void kernel_launch(void* const* d_in, const int* in_sizes, int n_in,
                              void* d_out, int out_size, void* d_ws, size_t ws_size,
                              hipStream_t stream) {
    (void)in_sizes; (void)n_in; (void)out_size;
    const float* x          = (const float*)d_in[0];
    const float* rots       = (const float*)d_in[1];
    const float* trans      = (const float*)d_in[2];
    const float* intrins    = (const float*)d_in[3];
    const float* post_rots  = (const float*)d_in[4];
    const float* post_trans = (const float*)d_in[5];
    float* out = (float*)d_out;

    float* wsf  = (float*)d_ws;
    float* mats = wsf + MATS_OFF;
    int*   wsi  = (int*)d_ws;
    int* count  = wsi + COUNT_OFF;
    int* fill   = wsi + FILL_OFF;
    int* offset = wsi + OFFSET_OFF;
    int* bsum   = wsi + BSUM_OFF;
    int* boff   = wsi + BOFF_OFF;
    int* pidx   = wsi + PIDX_OFF;
    int* plist  = wsi + PLIST_OFF;

    setup_kernel<<<1, 32, 0, stream>>>(rots, trans, intrins, post_rots, post_trans, mats);

    if (ws_size >= (size_t)WS_FLOATS * 4) {
        // zero count+fill (contiguous region)
        hipMemsetAsync(count, 0, (size_t)(2 * NVOX) * 4, stream);
        geom_kernel<<<NPRIME / 256, 256, 0, stream>>>(mats, pidx, count);
        scan1<<<NVOX / 256, 256, 0, stream>>>(count, offset, bsum);
        scan2<<<1, 1024, 0, stream>>>(bsum, boff, NVOX / 256);
        scan3<<<NVOX / 256, 256, 0, stream>>>(offset, boff);
        fill_kernel<<<NPRIME / 256, 256, 0, stream>>>(pidx, offset, fill, plist);
        pool_kernel<<<NVOX / 4, 256, 0, stream>>>(x, plist, offset, count, out);
    } else {
        hipMemsetAsync(out, 0, (size_t)NB * NC * NX0_ * NX1_ * 4, stream);
        scatter_direct<<<NPRIME / 4, 256, 0, stream>>>(x, mats, out);
    }
}

// Round 2
// 359.336 us; speedup vs baseline: 1.6075x; 1.6075x over previous
//
#include <hip/hip_runtime.h>
#include <cstddef>

// ---------------- problem constants (match reference) ----------------
#define NB   4
#define NN_  6
#define ND_  41
#define NFH  16
#define NFW  44
#define NC   64
#define NX0_ 200
#define NX1_ 200
#define NXY  (NX0_ * NX1_)                 // 40000
#define NCOL (NB * NN_ * ND_ * NFW)        // 43296 columns (each = 16 vertical pixels)

// ws: 24 floats per (b,n): M[9], Pinv[9], trans[3], post_trans[3]
#define MATS_FLOATS (NB * NN_ * 24)

// 3x3 inverse via adjugate. For these inputs (integer pinhole K, identity
// post_rots) every cofactor/det is exact in f32 and each division correctly
// rounded -> matches numpy's inv bit-for-bit. (Validated in round 1.)
__device__ __forceinline__ void inv3(const float* a, float* inv) {
    float c00 = __fsub_rn(__fmul_rn(a[4], a[8]), __fmul_rn(a[5], a[7]));
    float c01 = __fsub_rn(__fmul_rn(a[5], a[6]), __fmul_rn(a[3], a[8]));
    float c02 = __fsub_rn(__fmul_rn(a[3], a[7]), __fmul_rn(a[4], a[6]));
    float det = __fadd_rn(__fadd_rn(__fmul_rn(a[0], c00), __fmul_rn(a[1], c01)),
                          __fmul_rn(a[2], c02));
    inv[0] = __fdiv_rn(c00, det);
    inv[1] = __fdiv_rn(__fsub_rn(__fmul_rn(a[2], a[7]), __fmul_rn(a[1], a[8])), det);
    inv[2] = __fdiv_rn(__fsub_rn(__fmul_rn(a[1], a[5]), __fmul_rn(a[2], a[4])), det);
    inv[3] = __fdiv_rn(c01, det);
    inv[4] = __fdiv_rn(__fsub_rn(__fmul_rn(a[0], a[8]), __fmul_rn(a[2], a[6])), det);
    inv[5] = __fdiv_rn(__fsub_rn(__fmul_rn(a[2], a[3]), __fmul_rn(a[0], a[5])), det);
    inv[6] = __fdiv_rn(c02, det);
    inv[7] = __fdiv_rn(__fsub_rn(__fmul_rn(a[1], a[6]), __fmul_rn(a[0], a[7])), det);
    inv[8] = __fdiv_rn(__fsub_rn(__fmul_rn(a[0], a[4]), __fmul_rn(a[1], a[3])), det);
}

__global__ void setup_kernel(const float* __restrict__ rots,
                             const float* __restrict__ trans,
                             const float* __restrict__ intrins,
                             const float* __restrict__ post_rots,
                             const float* __restrict__ post_trans,
                             float* __restrict__ mats) {
    int t = threadIdx.x;
    if (t >= NB * NN_) return;
    const float* R  = rots      + t * 9;
    const float* K  = intrins   + t * 9;
    const float* PR = post_rots + t * 9;
    float Kinv[9], Pinv[9];
    inv3(K, Kinv);
    inv3(PR, Pinv);
    float* o = mats + t * 24;
    for (int i = 0; i < 3; ++i)
        for (int k = 0; k < 3; ++k) {
            float s = __fmul_rn(R[i * 3 + 0], Kinv[0 * 3 + k]);
            s = __fadd_rn(s, __fmul_rn(R[i * 3 + 1], Kinv[1 * 3 + k]));
            s = __fadd_rn(s, __fmul_rn(R[i * 3 + 2], Kinv[2 * 3 + k]));
            o[i * 3 + k] = s;
        }
    for (int i = 0; i < 9; ++i) o[9 + i] = Pinv[i];
    o[18] = trans[t * 3 + 0];
    o[19] = trans[t * 3 + 1];
    o[20] = trans[t * 3 + 2];
    o[21] = post_trans[t * 3 + 0];
    o[22] = post_trans[t * 3 + 1];
    o[23] = post_trans[t * 3 + 2];
}

// Voxel flat index (b*NXY + i0*NX1 + i1) for point (b,n,d,h,w), or -1.
// Numerics IDENTICAL to the round-1 passing kernel: _rn intrinsics only
// (no fma contraction), f64 linspace semantics for u, trunc-toward-zero.
__device__ __forceinline__ int compute_idx(int b, int n, int d, int h, int w,
                                           const float* __restrict__ mats) {
    const float* mp = mats + (b * NN_ + n) * 24;

    float u   = (w == NFW - 1) ? 703.0f : (float)((double)w * (703.0 / 43.0));
    float v   = __fmul_rn((float)h, 17.0f);   // 255/15 == 17 exactly
    float dep = (float)(4 + d);               // arange(4,45,1): exact ints

    float f0 = __fsub_rn(u, mp[21]);
    float f1 = __fsub_rn(v, mp[22]);
    float f2 = __fsub_rn(dep, mp[23]);

    float q0 = __fadd_rn(__fadd_rn(__fmul_rn(mp[9],  f0), __fmul_rn(mp[10], f1)), __fmul_rn(mp[11], f2));
    float q1 = __fadd_rn(__fadd_rn(__fmul_rn(mp[12], f0), __fmul_rn(mp[13], f1)), __fmul_rn(mp[14], f2));
    float q2 = __fadd_rn(__fadd_rn(__fmul_rn(mp[15], f0), __fmul_rn(mp[16], f1)), __fmul_rn(mp[17], f2));

    float r0 = __fmul_rn(q0, q2);
    float r1 = __fmul_rn(q1, q2);

    float g0 = __fadd_rn(__fadd_rn(__fadd_rn(__fmul_rn(mp[0], r0), __fmul_rn(mp[1], r1)), __fmul_rn(mp[2], q2)), mp[18]);
    float g1 = __fadd_rn(__fadd_rn(__fadd_rn(__fmul_rn(mp[3], r0), __fmul_rn(mp[4], r1)), __fmul_rn(mp[5], q2)), mp[19]);
    float g2 = __fadd_rn(__fadd_rn(__fadd_rn(__fmul_rn(mp[6], r0), __fmul_rn(mp[7], r1)), __fmul_rn(mp[8], q2)), mp[20]);

    float s0 = __fdiv_rn(__fsub_rn(g0, -50.0f), 0.5f);
    float s1 = __fdiv_rn(__fsub_rn(g1, -50.0f), 0.5f);
    float s2 = __fdiv_rn(__fsub_rn(g2, -10.0f), 20.0f);
    s0 = fminf(fmaxf(s0, -1e6f), 1e6f);
    s1 = fminf(fmaxf(s1, -1e6f), 1e6f);
    s2 = fminf(fmaxf(s2, -1e6f), 1e6f);
    int i0 = (int)s0;   // trunc toward zero == jnp.trunc().astype(int32)
    int i1 = (int)s1;
    int i2 = (int)s2;
    if (i0 >= 0 && i0 < NX0_ && i1 >= 0 && i1 < NX1_ && i2 >= 0 && i2 < 1)
        return b * NXY + i0 * NX1_ + i1;
    return -1;
}

// One 16-lane group per (b,n,d,w) column; lane l owns channels [4l,4l+4).
// All 16 vertical pixels of a column share one BEV voxel for these inputs
// (cam-y -> ego-z exactly; single z bin), so the 16 rows are summed in
// registers and flushed with 4 atomics/lane. The else-branch keeps it
// correct even if some h maps elsewhere (never relied upon).
__global__ __launch_bounds__(256) void col_pool(const float* __restrict__ x,
                                                const float* __restrict__ mats,
                                                float* __restrict__ out) {
    int cid  = blockIdx.x * 16 + (threadIdx.x >> 4);   // column id, NCOL=43296=2706*16
    int l    = threadIdx.x & 15;                       // lane-in-group: channel quad
    int w = cid % NFW; int t = cid / NFW;
    int d = t % ND_;   t /= ND_;
    int n = t % NN_;   int b = t / NN_;

    // each lane computes the voxel idx for h = l; broadcast within the group
    int myidx = compute_idx(b, n, d, l, w, mats);

    size_t pbase = ((size_t)((b * NN_ + n) * ND_ + d) * NFH) * NFW + w;  // p at h=0
    float4 sum = make_float4(0.f, 0.f, 0.f, 0.f);
    int first = -1;

    #pragma unroll
    for (int h = 0; h < 16; ++h) {
        int idxh = __shfl(myidx, h, 16);
        if (idxh >= 0) {
            const float4 val =
                *(const float4*)(x + (pbase + (size_t)h * NFW) * NC + l * 4);
            if (first < 0) first = idxh;
            if (idxh == first) {
                sum.x += val.x; sum.y += val.y; sum.z += val.z; sum.w += val.w;
            } else {                                  // rare/never: safety net
                int bb = idxh / NXY, xy = idxh % NXY;
                float* o = out + ((size_t)(bb * NC + l * 4)) * NXY + xy;
                atomicAdd(o,           val.x);
                atomicAdd(o + NXY,     val.y);
                atomicAdd(o + 2 * NXY, val.z);
                atomicAdd(o + 3 * NXY, val.w);
            }
        }
    }
    if (first >= 0) {
        int bb = first / NXY, xy = first % NXY;
        float* o = out + ((size_t)(bb * NC + l * 4)) * NXY + xy;
        atomicAdd(o,           sum.x);
        atomicAdd(o + NXY,     sum.y);
        atomicAdd(o + 2 * NXY, sum.z);
        atomicAdd(o + 3 * NXY, sum.w);
    }
}

extern "C" void kernel_launch(void* const* d_in, const int* in_sizes, int n_in,
                              void* d_out, int out_size, void* d_ws, size_t ws_size,
                              hipStream_t stream) {
    (void)in_sizes; (void)n_in; (void)out_size; (void)ws_size;
    const float* x          = (const float*)d_in[0];
    const float* rots       = (const float*)d_in[1];
    const float* trans      = (const float*)d_in[2];
    const float* intrins    = (const float*)d_in[3];
    const float* post_rots  = (const float*)d_in[4];
    const float* post_trans = (const float*)d_in[5];
    float* out  = (float*)d_out;
    float* mats = (float*)d_ws;   // 576 floats

    setup_kernel<<<1, 32, 0, stream>>>(rots, trans, intrins, post_rots, post_trans, mats);
    // out is re-poisoned to 0xAA before every timed launch -> zero it each call
    hipMemsetAsync(out, 0, (size_t)NB * NC * NXY * sizeof(float), stream);
    col_pool<<<NCOL / 16, 256, 0, stream>>>(x, mats, out);
}

// Round 3
// 326.395 us; speedup vs baseline: 1.7698x; 1.1009x over previous
//
#include <hip/hip_runtime.h>
#include <cstddef>

// ---------------- problem constants (match reference) ----------------
#define NB   4
#define NN_  6
#define ND_  41
#define NFH  16
#define NFW  44
#define NC   64
#define NX0_ 200
#define NX1_ 200
#define NXY  (NX0_ * NX1_)                 // 40000
#define NCOL (NB * NN_ * ND_ * NFW)        // 43296 columns (each = 16 vertical pixels)

// 3x3 inverse via adjugate. For these inputs (integer pinhole K, identity
// post_rots) every cofactor/det is exact in f32 and each division correctly
// rounded -> matches numpy's inv bit-for-bit. (Validated rounds 1-2.)
__device__ __forceinline__ void inv3(const float* a, float* inv) {
    float c00 = __fsub_rn(__fmul_rn(a[4], a[8]), __fmul_rn(a[5], a[7]));
    float c01 = __fsub_rn(__fmul_rn(a[5], a[6]), __fmul_rn(a[3], a[8]));
    float c02 = __fsub_rn(__fmul_rn(a[3], a[7]), __fmul_rn(a[4], a[6]));
    float det = __fadd_rn(__fadd_rn(__fmul_rn(a[0], c00), __fmul_rn(a[1], c01)),
                          __fmul_rn(a[2], c02));
    inv[0] = __fdiv_rn(c00, det);
    inv[1] = __fdiv_rn(__fsub_rn(__fmul_rn(a[2], a[7]), __fmul_rn(a[1], a[8])), det);
    inv[2] = __fdiv_rn(__fsub_rn(__fmul_rn(a[1], a[5]), __fmul_rn(a[2], a[4])), det);
    inv[3] = __fdiv_rn(c01, det);
    inv[4] = __fdiv_rn(__fsub_rn(__fmul_rn(a[0], a[8]), __fmul_rn(a[2], a[6])), det);
    inv[5] = __fdiv_rn(__fsub_rn(__fmul_rn(a[2], a[3]), __fmul_rn(a[0], a[5])), det);
    inv[6] = __fdiv_rn(c02, det);
    inv[7] = __fdiv_rn(__fsub_rn(__fmul_rn(a[1], a[6]), __fmul_rn(a[0], a[7])), det);
    inv[8] = __fdiv_rn(__fsub_rn(__fmul_rn(a[0], a[4]), __fmul_rn(a[1], a[3])), det);
}

__global__ void setup_kernel(const float* __restrict__ rots,
                             const float* __restrict__ trans,
                             const float* __restrict__ intrins,
                             const float* __restrict__ post_rots,
                             const float* __restrict__ post_trans,
                             float* __restrict__ mats) {
    int t = threadIdx.x;
    if (t >= NB * NN_) return;
    const float* R  = rots      + t * 9;
    const float* K  = intrins   + t * 9;
    const float* PR = post_rots + t * 9;
    float Kinv[9], Pinv[9];
    inv3(K, Kinv);
    inv3(PR, Pinv);
    float* o = mats + t * 24;
    for (int i = 0; i < 3; ++i)
        for (int k = 0; k < 3; ++k) {
            float s = __fmul_rn(R[i * 3 + 0], Kinv[0 * 3 + k]);
            s = __fadd_rn(s, __fmul_rn(R[i * 3 + 1], Kinv[1 * 3 + k]));
            s = __fadd_rn(s, __fmul_rn(R[i * 3 + 2], Kinv[2 * 3 + k]));
            o[i * 3 + k] = s;
        }
    for (int i = 0; i < 9; ++i) o[9 + i] = Pinv[i];
    o[18] = trans[t * 3 + 0];
    o[19] = trans[t * 3 + 1];
    o[20] = trans[t * 3 + 2];
    o[21] = post_trans[t * 3 + 0];
    o[22] = post_trans[t * 3 + 1];
    o[23] = post_trans[t * 3 + 2];
}

// Voxel flat index (b*NXY + i0*NX1 + i1) for point (b,n,d,h,w), or -1.
// Numerics IDENTICAL to the passing rounds: _rn intrinsics only (no fma
// contraction), f64 linspace semantics for u, trunc-toward-zero.
__device__ __forceinline__ int compute_idx(int b, int n, int d, int h, int w,
                                           const float* __restrict__ mats) {
    const float* mp = mats + (b * NN_ + n) * 24;

    float u   = (w == NFW - 1) ? 703.0f : (float)((double)w * (703.0 / 43.0));
    float v   = __fmul_rn((float)h, 17.0f);   // 255/15 == 17 exactly
    float dep = (float)(4 + d);               // arange(4,45,1): exact ints

    float f0 = __fsub_rn(u, mp[21]);
    float f1 = __fsub_rn(v, mp[22]);
    float f2 = __fsub_rn(dep, mp[23]);

    float q0 = __fadd_rn(__fadd_rn(__fmul_rn(mp[9],  f0), __fmul_rn(mp[10], f1)), __fmul_rn(mp[11], f2));
    float q1 = __fadd_rn(__fadd_rn(__fmul_rn(mp[12], f0), __fmul_rn(mp[13], f1)), __fmul_rn(mp[14], f2));
    float q2 = __fadd_rn(__fadd_rn(__fmul_rn(mp[15], f0), __fmul_rn(mp[16], f1)), __fmul_rn(mp[17], f2));

    float r0 = __fmul_rn(q0, q2);
    float r1 = __fmul_rn(q1, q2);

    float g0 = __fadd_rn(__fadd_rn(__fadd_rn(__fmul_rn(mp[0], r0), __fmul_rn(mp[1], r1)), __fmul_rn(mp[2], q2)), mp[18]);
    float g1 = __fadd_rn(__fadd_rn(__fadd_rn(__fmul_rn(mp[3], r0), __fmul_rn(mp[4], r1)), __fmul_rn(mp[5], q2)), mp[19]);
    float g2 = __fadd_rn(__fadd_rn(__fadd_rn(__fmul_rn(mp[6], r0), __fmul_rn(mp[7], r1)), __fmul_rn(mp[8], q2)), mp[20]);

    float s0 = __fdiv_rn(__fsub_rn(g0, -50.0f), 0.5f);
    float s1 = __fdiv_rn(__fsub_rn(g1, -50.0f), 0.5f);
    float s2 = __fdiv_rn(__fsub_rn(g2, -10.0f), 20.0f);
    s0 = fminf(fmaxf(s0, -1e6f), 1e6f);
    s1 = fminf(fmaxf(s1, -1e6f), 1e6f);
    s2 = fminf(fmaxf(s2, -1e6f), 1e6f);
    int i0 = (int)s0;   // trunc toward zero == jnp.trunc().astype(int32)
    int i1 = (int)s1;
    int i2 = (int)s2;
    if (i0 >= 0 && i0 < NX0_ && i1 >= 0 && i1 < NX1_ && i2 >= 0 && i2 < 1)
        return b * NXY + i0 * NX1_ + i1;
    return -1;
}

// One 16-lane group per (b,n,d,w) column; lane l owns channels [4l,4l+4).
// The BEV (i0,i1) cell is exactly h-independent for these inputs (M[0][1] and
// M[1][1] are exactly 0.0f); only z-validity varies with h. So: one uniform
// column-level branch, then 16 UNCONDITIONAL independent float4 loads
// (pipelined by the compiler) and a branchless mask-multiply accumulate —
// which mirrors the reference's `feats * w`. Slow path kept for safety.
__global__ __launch_bounds__(256) void col_pool(const float* __restrict__ x,
                                                const float* __restrict__ mats,
                                                float* __restrict__ out) {
    int cid  = blockIdx.x * 16 + (threadIdx.x >> 4);   // NCOL = 2706*16
    int l    = threadIdx.x & 15;                       // channel quad
    int w = cid % NFW; int t = cid / NFW;
    int d = t % ND_;   t /= ND_;
    int n = t % NN_;   int b = t / NN_;

    int myidx = compute_idx(b, n, d, l, w, mats);

    // gather all 16 per-h indices into registers (no loop-carried deps)
    int idx[16];
    #pragma unroll
    for (int h = 0; h < 16; ++h) idx[h] = __shfl(myidx, h, 16);

    int common = -1;
    bool allsame = true;
    #pragma unroll
    for (int h = 0; h < 16; ++h) {
        if (idx[h] >= 0) {
            if (common < 0) common = idx[h];
            else if (idx[h] != common) allsame = false;
        }
    }
    if (common < 0) return;   // whole column dropped: skip all loads

    const float4* xp = (const float4*)
        (x + (((size_t)((b * NN_ + n) * ND_ + d) * NFH) * NFW + w) * NC) + l;
    const int HSTRIDE = NFW * (NC / 4);   // float4 stride between h rows

    // 16 independent loads — compiler can keep all in flight
    float4 v[16];
    #pragma unroll
    for (int h = 0; h < 16; ++h) v[h] = xp[h * HSTRIDE];

    if (__builtin_expect(allsame, 1)) {
        // branchless mask-multiply accumulate (== reference's feats*w)
        float4 a0 = make_float4(0.f, 0.f, 0.f, 0.f);
        float4 a1 = make_float4(0.f, 0.f, 0.f, 0.f);
        #pragma unroll
        for (int h = 0; h < 16; h += 2) {
            float m0 = (idx[h]     >= 0) ? 1.0f : 0.0f;
            float m1 = (idx[h + 1] >= 0) ? 1.0f : 0.0f;
            a0.x += v[h].x * m0;     a0.y += v[h].y * m0;
            a0.z += v[h].z * m0;     a0.w += v[h].w * m0;
            a1.x += v[h + 1].x * m1; a1.y += v[h + 1].y * m1;
            a1.z += v[h + 1].z * m1; a1.w += v[h + 1].w * m1;
        }
        a0.x += a1.x; a0.y += a1.y; a0.z += a1.z; a0.w += a1.w;
        int bb = common / NXY, xy = common % NXY;
        float* o = out + ((size_t)(bb * NC + l * 4)) * NXY + xy;
        atomicAdd(o,           a0.x);
        atomicAdd(o + NXY,     a0.y);
        atomicAdd(o + 2 * NXY, a0.z);
        atomicAdd(o + 3 * NXY, a0.w);
    } else {
        // safety net (provably unreachable for these inputs)
        #pragma unroll
        for (int h = 0; h < 16; ++h) {
            if (idx[h] >= 0) {
                int bb = idx[h] / NXY, xy = idx[h] % NXY;
                float* o = out + ((size_t)(bb * NC + l * 4)) * NXY + xy;
                atomicAdd(o,           v[h].x);
                atomicAdd(o + NXY,     v[h].y);
                atomicAdd(o + 2 * NXY, v[h].z);
                atomicAdd(o + 3 * NXY, v[h].w);
            }
        }
    }
}

extern "C" void kernel_launch(void* const* d_in, const int* in_sizes, int n_in,
                              void* d_out, int out_size, void* d_ws, size_t ws_size,
                              hipStream_t stream) {
    (void)in_sizes; (void)n_in; (void)out_size; (void)ws_size;
    const float* x          = (const float*)d_in[0];
    const float* rots       = (const float*)d_in[1];
    const float* trans      = (const float*)d_in[2];
    const float* intrins    = (const float*)d_in[3];
    const float* post_rots  = (const float*)d_in[4];
    const float* post_trans = (const float*)d_in[5];
    float* out  = (float*)d_out;
    float* mats = (float*)d_ws;   // 576 floats

    setup_kernel<<<1, 32, 0, stream>>>(rots, trans, intrins, post_rots, post_trans, mats);
    // out is re-poisoned to 0xAA before every timed launch -> zero it each call
    hipMemsetAsync(out, 0, (size_t)NB * NC * NXY * sizeof(float), stream);
    col_pool<<<NCOL / 16, 256, 0, stream>>>(x, mats, out);
}